// Round 1
// baseline (513.076 us; speedup 1.0000x reference)
//
#include <hip/hip_runtime.h>
#include <math.h>

#define B_SZ 256
#define N_SZ 1024
#define NCL  101       // C+1
#define D_SZ 256
#define NH   16
#define APAD 260
#define NEGV (-1000000000.0f)

// d_ws layout: [0] int mode flag; +1024B: uv (B*D floats); then uvc (B*D floats)

// mask encoding: 0 = int32 0/1, 1 = byte 0/1, 2 = float32 0.0/1.0
__device__ __forceinline__ bool mask_at(const void* p, long idx, int mode) {
  if (mode == 0) return ((const int*)p)[idx] != 0;
  if (mode == 1) return ((const unsigned char*)p)[idx] != 0;
  return ((const float*)p)[idx] != 0.0f;
}

__global__ void detect_mode_kernel(const unsigned int* m, int* flag) {
  if (threadIdx.x == 0 && blockIdx.x == 0) {
    bool isf = false, nonbin = false;
    for (int i = 0; i < 256; ++i) {
      unsigned int v = m[i];
      if (v == 0x3F800000u) isf = true;
      else if (v > 1u) nonbin = true;
    }
    *flag = isf ? 2 : (nonbin ? 1 : 0);
  }
}

// One block per batch; 512 threads; fused uv (~mask) and uvc (~(mask|cluster_mask)) means.
__global__ __launch_bounds__(512) void mean_kernel(
    const float* __restrict__ node, const void* __restrict__ mask,
    const void* __restrict__ cmask, const int* __restrict__ flag,
    float* __restrict__ uv, float* __restrict__ uvc) {
  const int b = blockIdx.x, tid = threadIdx.x;
  const int mode = *flag;
  __shared__ float f1[N_SZ], f2[N_SZ];
  __shared__ int wcnt1[8], wcnt2[8];
  __shared__ float red[8][D_SZ];

  int c1 = 0, c2 = 0;
  for (int n = tid; n < N_SZ; n += 512) {
    const bool m1 = mask_at(mask,  (long)b * N_SZ + n, mode);
    const bool m2 = mask_at(cmask, (long)b * N_SZ + n, mode);
    const int k1 = m1 ? 0 : 1;
    const int k2 = (m1 || m2) ? 0 : 1;
    f1[n] = (float)k1; f2[n] = (float)k2;
    c1 += k1; c2 += k2;
  }
  for (int off = 32; off > 0; off >>= 1) {
    c1 += __shfl_down(c1, off);
    c2 += __shfl_down(c2, off);
  }
  if ((tid & 63) == 0) { wcnt1[tid >> 6] = c1; wcnt2[tid >> 6] = c2; }
  __syncthreads();
  int t1 = 0, t2 = 0;
  #pragma unroll
  for (int w = 0; w < 8; ++w) { t1 += wcnt1[w]; t2 += wcnt2[w]; }
  const float den1 = fmaxf((float)t1, 1.0f);
  const float den2 = fmaxf((float)t2, 1.0f);

  const int rg = tid >> 6;          // row group 0..7 (one wave per group)
  const int c4 = (tid & 63) << 2;   // column (float4)
  const float* base = node + (size_t)b * N_SZ * D_SZ + c4;
  float4 s1 = {0.f,0.f,0.f,0.f}, s2 = {0.f,0.f,0.f,0.f};
  for (int n = rg; n < N_SZ; n += 8) {
    const float4 x = *(const float4*)(base + (size_t)n * D_SZ);
    const float k1 = f1[n], k2 = f2[n];
    s1.x = fmaf(x.x, k1, s1.x); s1.y = fmaf(x.y, k1, s1.y);
    s1.z = fmaf(x.z, k1, s1.z); s1.w = fmaf(x.w, k1, s1.w);
    s2.x = fmaf(x.x, k2, s2.x); s2.y = fmaf(x.y, k2, s2.y);
    s2.z = fmaf(x.z, k2, s2.z); s2.w = fmaf(x.w, k2, s2.w);
  }
  *(float4*)&red[rg][c4] = s1;
  __syncthreads();
  if (tid < D_SZ) {
    float t = 0.f;
    #pragma unroll
    for (int r = 0; r < 8; ++r) t += red[r][tid];
    uv[b * D_SZ + tid] = t / den1;
  }
  __syncthreads();
  *(float4*)&red[rg][c4] = s2;
  __syncthreads();
  if (tid < D_SZ) {
    float t = 0.f;
    #pragma unroll
    for (int r = 0; r < 8; ++r) t += red[r][tid];
    uvc[b * D_SZ + tid] = t / den2;
  }
}

struct __align__(16) SMem {
  float At[16][APAD];                               // A chunk (16 rows)
  union { float tT[NH][APAD]; float uB[NH][APAD]; } tu;
  float sc[NH][104];                                // scores -> attn
  float ctx[3 * D_SZ];
  float q[D_SZ];
  float g[D_SZ];
  float go[D_SZ];
  float w[D_SZ];
  float logits[104];
  int   vm[104];
  float lse_s;
  int   sel_s;
};

__global__ __launch_bounds__(256) void main_kernel(
    const float* __restrict__ depot, const float* __restrict__ cluster,
    const float* __restrict__ current, const void* __restrict__ vcm,
    const int* __restrict__ flag,
    const float* __restrict__ Wq, const float* __restrict__ Wk,
    const float* __restrict__ Wv, const float* __restrict__ Wks,
    const float* __restrict__ Wo,
    const float* __restrict__ uv, const float* __restrict__ uvc,
    float* __restrict__ out) {
  __shared__ SMem S;
  const int b = blockIdx.x, tid = threadIdx.x;
  const int mode = *flag;
  const float* Ab = cluster + (size_t)b * NCL * D_SZ;

  // --- vm + context ---
  if (tid < NCL) S.vm[tid] = mask_at(vcm, (long)b * NCL + tid, mode) ? 1 : 0;
  S.ctx[tid]       = uv[b * D_SZ + tid];
  S.ctx[256 + tid] = current[b * D_SZ + tid];
  S.ctx[512 + tid] = depot[b * D_SZ + tid];
  __syncthreads();
  if (tid == 0) {  // vm[0] = !all(vm[1:])
    int all1 = 1;
    for (int c = 1; c < NCL; ++c) all1 &= S.vm[c];
    S.vm[0] = all1 ? 0 : 1;
  }

  // --- q[j] = ctx . Wq[:,j], j = tid ---
  {
    float a0 = 0.f, a1 = 0.f, a2 = 0.f, a3 = 0.f;
    for (int i = 0; i < 3 * D_SZ; i += 4) {
      a0 = fmaf(S.ctx[i + 0], Wq[(size_t)(i + 0) * D_SZ + tid], a0);
      a1 = fmaf(S.ctx[i + 1], Wq[(size_t)(i + 1) * D_SZ + tid], a1);
      a2 = fmaf(S.ctx[i + 2], Wq[(size_t)(i + 2) * D_SZ + tid], a2);
      a3 = fmaf(S.ctx[i + 3], Wq[(size_t)(i + 3) * D_SZ + tid], a3);
    }
    S.q[tid] = (a0 + a1) + (a2 + a3);
  }
  __syncthreads();

  // --- tT[h][i] = sum_e Wk[i, h*16+e] * q[h*16+e] ---
  {
    const int h = tid & 15, i0 = tid >> 4;
    float qh[16];
    #pragma unroll
    for (int e = 0; e < 16; ++e) qh[e] = S.q[h * 16 + e];
    for (int k = 0; k < 16; ++k) {
      const int i = i0 + 16 * k;
      const float* wr = Wk + (size_t)i * D_SZ + h * 16;
      float acc = 0.f;
      #pragma unroll
      for (int e = 0; e < 16; ++e) acc = fmaf(wr[e], qh[e], acc);
      S.tu.tT[h][i] = acc;
    }
  }
  __syncthreads();

  // --- scores[h][c] = 0.25 * sum_i A[c,i] * tT[h][i], chunked over c ---
  for (int ch = 0; ch < 7; ++ch) {
    const int r0 = ch * 16;
    for (int x = tid; x < 16 * 64; x += 256) {
      const int r = x >> 6, cc = (x & 63) << 2;
      if (r0 + r < NCL) {
        const float4 v = *(const float4*)(Ab + (size_t)(r0 + r) * D_SZ + cc);
        *(float4*)&S.At[r][cc] = v;
      }
    }
    __syncthreads();
    {
      const int h = tid >> 4, cl = tid & 15, c = r0 + cl;
      float p0 = 0.f, p1 = 0.f, p2 = 0.f, p3 = 0.f;
      for (int i = 0; i < D_SZ; i += 4) {
        const float4 av = *(const float4*)&S.At[cl][i];
        const float4 tv = *(const float4*)&S.tu.tT[h][i];
        p0 = fmaf(av.x, tv.x, p0);
        p1 = fmaf(av.y, tv.y, p1);
        p2 = fmaf(av.z, tv.z, p2);
        p3 = fmaf(av.w, tv.w, p3);
      }
      if (c < NCL) {
        float sv = 0.25f * ((p0 + p1) + (p2 + p3));
        if (S.vm[c]) sv = NEGV;
        S.sc[h][c] = sv;
      }
    }
    __syncthreads();
  }

  // --- softmax per head (16 lanes per head) ---
  {
    const int h = tid >> 4, j = tid & 15;
    float m = -3.0e38f;
    for (int c = j; c < NCL; c += 16) m = fmaxf(m, S.sc[h][c]);
    #pragma unroll
    for (int off = 8; off > 0; off >>= 1) m = fmaxf(m, __shfl_xor(m, off, 16));
    float ssum = 0.f;
    for (int c = j; c < NCL; c += 16) {
      const float e = expf(S.sc[h][c] - m);
      S.sc[h][c] = e;
      ssum += e;
    }
    #pragma unroll
    for (int off = 8; off > 0; off >>= 1) ssum += __shfl_xor(ssum, off, 16);
    const float inv = 1.0f / ssum;
    for (int c = j; c < NCL; c += 16) S.sc[h][c] *= inv;
  }
  __syncthreads();

  // --- u[h][i] = sum_c attn[h,c] * A[c,i]; thread owns column i = tid ---
  {
    float u[16];
    #pragma unroll
    for (int h = 0; h < 16; ++h) u[h] = 0.f;
    for (int ch = 0; ch < 7; ++ch) {
      const int r0 = ch * 16;
      for (int x = tid; x < 16 * 64; x += 256) {
        const int r = x >> 6, cc = (x & 63) << 2;
        if (r0 + r < NCL) {
          const float4 v = *(const float4*)(Ab + (size_t)(r0 + r) * D_SZ + cc);
          *(float4*)&S.At[r][cc] = v;
        }
      }
      __syncthreads();
      const int cmax = (NCL - r0 < 16) ? (NCL - r0) : 16;
      for (int cl = 0; cl < cmax; ++cl) {
        const float a = S.At[cl][tid];
        const int c = r0 + cl;
        #pragma unroll
        for (int h = 0; h < 16; ++h) u[h] = fmaf(S.sc[h][c], a, u[h]);
      }
      __syncthreads();
    }
    #pragma unroll
    for (int h = 0; h < 16; ++h) S.tu.uB[h][tid] = u[h];  // tT dead now
  }
  __syncthreads();

  // --- glimpse: g[h*16+e] = sum_i u[h][i] * Wv[i, h*16+e]; (h*16+e) == tid ---
  {
    const int h = tid >> 4;
    float p0 = 0.f, p1 = 0.f, p2 = 0.f, p3 = 0.f;
    for (int i = 0; i < D_SZ; i += 4) {
      p0 = fmaf(S.tu.uB[h][i + 0], Wv[(size_t)(i + 0) * D_SZ + tid], p0);
      p1 = fmaf(S.tu.uB[h][i + 1], Wv[(size_t)(i + 1) * D_SZ + tid], p1);
      p2 = fmaf(S.tu.uB[h][i + 2], Wv[(size_t)(i + 2) * D_SZ + tid], p2);
      p3 = fmaf(S.tu.uB[h][i + 3], Wv[(size_t)(i + 3) * D_SZ + tid], p3);
    }
    S.g[tid] = (p0 + p1) + (p2 + p3);
  }
  __syncthreads();

  // --- go[j] = sum_d g[d] * Wo[d,j] ---
  {
    float p0 = 0.f, p1 = 0.f, p2 = 0.f, p3 = 0.f;
    for (int d = 0; d < D_SZ; d += 4) {
      p0 = fmaf(S.g[d + 0], Wo[(size_t)(d + 0) * D_SZ + tid], p0);
      p1 = fmaf(S.g[d + 1], Wo[(size_t)(d + 1) * D_SZ + tid], p1);
      p2 = fmaf(S.g[d + 2], Wo[(size_t)(d + 2) * D_SZ + tid], p2);
      p3 = fmaf(S.g[d + 3], Wo[(size_t)(d + 3) * D_SZ + tid], p3);
    }
    S.go[tid] = (p0 + p1) + (p2 + p3);
  }
  __syncthreads();

  // --- w[i] = sum_j Wks[i,j] * go[j]; thread streams row i = tid ---
  {
    const float* wr = Wks + (size_t)tid * D_SZ;
    float p0 = 0.f, p1 = 0.f, p2 = 0.f, p3 = 0.f;
    for (int j = 0; j < D_SZ; j += 4) {
      const float4 w4 = *(const float4*)&wr[j];
      p0 = fmaf(w4.x, S.go[j + 0], p0);
      p1 = fmaf(w4.y, S.go[j + 1], p1);
      p2 = fmaf(w4.z, S.go[j + 2], p2);
      p3 = fmaf(w4.w, S.go[j + 3], p3);
    }
    S.w[tid] = (p0 + p1) + (p2 + p3);
  }
  __syncthreads();

  // --- logits[c] = tanh((A[c,:].w)/16)*10, masked ---
  if (tid < NCL) {
    const float* ar = Ab + (size_t)tid * D_SZ;
    float p0 = 0.f, p1 = 0.f, p2 = 0.f, p3 = 0.f;
    for (int i = 0; i < D_SZ; i += 4) {
      const float4 a4 = *(const float4*)&ar[i];
      p0 = fmaf(a4.x, S.w[i + 0], p0);
      p1 = fmaf(a4.y, S.w[i + 1], p1);
      p2 = fmaf(a4.z, S.w[i + 2], p2);
      p3 = fmaf(a4.w, S.w[i + 3], p3);
    }
    float l = ((p0 + p1) + (p2 + p3)) * 0.0625f;
    l = tanhf(l) * 10.0f;
    if (S.vm[tid]) l = NEGV;
    S.logits[tid] = l;
  }
  __syncthreads();

  // --- logsumexp + argmax (wave 0) ---
  if (tid < 64) {
    float bv = -3.0e38f; int bi = 0;
    for (int c = tid; c < NCL; c += 64) {
      const float v = S.logits[c];
      if (v > bv) { bv = v; bi = c; }
    }
    #pragma unroll
    for (int off = 32; off > 0; off >>= 1) {
      const float ov = __shfl_xor(bv, off);
      const int   oi = __shfl_xor(bi, off);
      if (ov > bv || (ov == bv && oi < bi)) { bv = ov; bi = oi; }
    }
    float ss = 0.f;
    for (int c = tid; c < NCL; c += 64) ss += expf(S.logits[c] - bv);
    #pragma unroll
    for (int off = 32; off > 0; off >>= 1) ss += __shfl_xor(ss, off);
    if (tid == 0) { S.lse_s = bv + logf(ss); S.sel_s = bi; }
  }
  __syncthreads();

  // --- outputs ---
  // layout: init_aug [B,1024] @0; guid_emb [B,256] @262144; guid [B] @327680; clu_prob [B,101] @327936
  const float lse = S.lse_s;
  const int sel = S.sel_s;
  if (tid < NCL) out[327936 + b * NCL + tid] = S.logits[tid] - lse;
  if (tid == 0)  out[327680 + b] = (float)sel;
  const float se = Ab[(size_t)sel * D_SZ + tid];
  out[262144 + b * D_SZ + tid] = se;
  float* ia = out + (size_t)b * 1024;
  ia[tid]       = uvc[b * D_SZ + tid];
  ia[256 + tid] = current[b * D_SZ + tid];
  ia[512 + tid] = se;
  ia[768 + tid] = depot[b * D_SZ + tid];
}

extern "C" void kernel_launch(void* const* d_in, const int* in_sizes, int n_in,
                              void* d_out, int out_size, void* d_ws, size_t ws_size,
                              hipStream_t stream) {
  const float* depot   = (const float*)d_in[0];
  const float* cluster = (const float*)d_in[1];
  const float* current = (const float*)d_in[2];
  const float* node    = (const float*)d_in[3];
  const void*  mask    = d_in[4];
  const void*  cmask   = d_in[5];
  const void*  vcm     = d_in[6];
  const float* Wq  = (const float*)d_in[7];
  const float* Wk  = (const float*)d_in[8];
  const float* Wv  = (const float*)d_in[9];
  const float* Wks = (const float*)d_in[10];
  const float* Wo  = (const float*)d_in[11];
  float* out = (float*)d_out;

  int*   flag = (int*)d_ws;
  float* uv   = (float*)((char*)d_ws + 1024);
  float* uvc  = (float*)((char*)d_ws + 1024 + (size_t)B_SZ * D_SZ * 4);

  hipLaunchKernelGGL(detect_mode_kernel, dim3(1), dim3(64), 0, stream,
                     (const unsigned int*)mask, flag);
  hipLaunchKernelGGL(mean_kernel, dim3(B_SZ), dim3(512), 0, stream,
                     node, mask, cmask, flag, uv, uvc);
  hipLaunchKernelGGL(main_kernel, dim3(B_SZ), dim3(256), 0, stream,
                     depot, cluster, current, vcm, flag,
                     Wq, Wk, Wv, Wks, Wo, uv, uvc, out);
}

// Round 2
// 499.311 us; speedup vs baseline: 1.0276x; 1.0276x over previous
//
#include <hip/hip_runtime.h>
#include <math.h>

#define B_SZ 256
#define N_SZ 1024
#define NCL  101       // C+1
#define D_SZ 256
#define NH   16
#define APAD 260
#define NEGV (-1000000000.0f)

// d_ws layout:
//   [0]        int mode flag
//   +1024B     counts  [B][8][2] ints   (16 KB)
//   +17408B    partials[B][8][2][256] floats (4 MB)

// mask encoding: 0 = int32 0/1, 1 = byte 0/1, 2 = float32 0.0/1.0
__device__ __forceinline__ bool mask_at(const void* p, long idx, int mode) {
  if (mode == 0) return ((const int*)p)[idx] != 0;
  if (mode == 1) return ((const unsigned char*)p)[idx] != 0;
  return ((const float*)p)[idx] != 0.0f;
}

__global__ void detect_mode_kernel(const unsigned int* m, int* flag) {
  if (threadIdx.x == 0 && blockIdx.x == 0) {
    bool isf = false, nonbin = false;
    for (int i = 0; i < 256; ++i) {
      unsigned int v = m[i];
      if (v == 0x3F800000u) isf = true;
      else if (v > 1u) nonbin = true;
    }
    *flag = isf ? 2 : (nonbin ? 1 : 0);
  }
}

// 2048 blocks (b*8+s) x 256 threads; block handles 128 rows of batch b.
// 8 blocks/CU, 32 waves/CU -> enough in-flight loads to reach HBM BW.
__global__ __launch_bounds__(256) void mean_partial_kernel(
    const float* __restrict__ node, const void* __restrict__ mask,
    const void* __restrict__ cmask, const int* __restrict__ flag,
    int* __restrict__ counts, float* __restrict__ partials) {
  const int bs = blockIdx.x;
  const int b = bs >> 3, s = bs & 7;
  const int tid = threadIdx.x;
  const int mode = *flag;
  const int r0 = s * 128;
  __shared__ float f1[128], f2[128];
  __shared__ int wc1[2], wc2[2];
  __shared__ float red[4][D_SZ];

  int c1 = 0, c2 = 0;
  if (tid < 128) {
    const long idx = (long)b * N_SZ + r0 + tid;
    const bool m1 = mask_at(mask, idx, mode);
    const bool m2 = mask_at(cmask, idx, mode);
    const int k1 = m1 ? 0 : 1;
    const int k2 = (m1 || m2) ? 0 : 1;
    f1[tid] = (float)k1; f2[tid] = (float)k2;
    c1 = k1; c2 = k2;
  }
  #pragma unroll
  for (int off = 32; off > 0; off >>= 1) {
    c1 += __shfl_down(c1, off);
    c2 += __shfl_down(c2, off);
  }
  if (tid == 0)  { wc1[0] = c1; wc2[0] = c2; }
  if (tid == 64) { wc1[1] = c1; wc2[1] = c2; }
  __syncthreads();
  if (tid == 0) {
    counts[bs * 2 + 0] = wc1[0] + wc1[1];
    counts[bs * 2 + 1] = wc2[0] + wc2[1];
  }

  const int rg = tid >> 6;          // wave id 0..3 -> owns 32 rows
  const int c4 = (tid & 63) << 2;   // float4 column
  const float* base = node + ((size_t)b * N_SZ + r0) * D_SZ + c4;
  float4 s1 = {0.f,0.f,0.f,0.f}, s2 = {0.f,0.f,0.f,0.f};
  #pragma unroll 8
  for (int k = 0; k < 32; ++k) {
    const int row = rg * 32 + k;
    const float4 x = *(const float4*)(base + (size_t)row * D_SZ);
    const float k1 = f1[row], k2 = f2[row];
    s1.x = fmaf(x.x, k1, s1.x); s1.y = fmaf(x.y, k1, s1.y);
    s1.z = fmaf(x.z, k1, s1.z); s1.w = fmaf(x.w, k1, s1.w);
    s2.x = fmaf(x.x, k2, s2.x); s2.y = fmaf(x.y, k2, s2.y);
    s2.z = fmaf(x.z, k2, s2.z); s2.w = fmaf(x.w, k2, s2.w);
  }
  *(float4*)&red[rg][c4] = s1;
  __syncthreads();
  {
    float t = red[0][tid] + red[1][tid] + red[2][tid] + red[3][tid];
    partials[((size_t)bs * 2 + 0) * D_SZ + tid] = t;
  }
  __syncthreads();
  *(float4*)&red[rg][c4] = s2;
  __syncthreads();
  {
    float t = red[0][tid] + red[1][tid] + red[2][tid] + red[3][tid];
    partials[((size_t)bs * 2 + 1) * D_SZ + tid] = t;
  }
}

struct __align__(16) SMem {
  float At[16][APAD];                               // A chunk (16 rows)
  union { float tT[NH][APAD]; float uB[NH][APAD]; } tu;
  float sc[NH][104];                                // scores -> attn
  float ctx[3 * D_SZ];
  float q[D_SZ];
  float g[D_SZ];
  float go[D_SZ];
  float w[D_SZ];
  float logits[104];
  int   vm[104];
  float lse_s;
  int   sel_s;
};

__global__ __launch_bounds__(256) void main_kernel(
    const float* __restrict__ depot, const float* __restrict__ cluster,
    const float* __restrict__ current, const void* __restrict__ vcm,
    const int* __restrict__ flag,
    const float* __restrict__ Wq, const float* __restrict__ Wk,
    const float* __restrict__ Wv, const float* __restrict__ Wks,
    const float* __restrict__ Wo,
    const int* __restrict__ counts, const float* __restrict__ partials,
    float* __restrict__ out) {
  __shared__ SMem S;
  const int b = blockIdx.x, tid = threadIdx.x;
  const int mode = *flag;
  const float* Ab = cluster + (size_t)b * NCL * D_SZ;

  // --- fused 8-way mean reduction: uv -> ctx[0:256], uvc kept in register ---
  float uvv = 0.f, uvcv = 0.f;
  #pragma unroll
  for (int s = 0; s < 8; ++s) {
    uvv  += partials[((size_t)(b * 8 + s) * 2 + 0) * D_SZ + tid];
    uvcv += partials[((size_t)(b * 8 + s) * 2 + 1) * D_SZ + tid];
  }
  int t1 = 0, t2 = 0;
  #pragma unroll
  for (int s = 0; s < 8; ++s) {
    t1 += counts[(b * 8 + s) * 2 + 0];
    t2 += counts[(b * 8 + s) * 2 + 1];
  }
  const float uvcval = uvcv / fmaxf((float)t2, 1.0f);

  // --- vm + context ---
  if (tid < NCL) S.vm[tid] = mask_at(vcm, (long)b * NCL + tid, mode) ? 1 : 0;
  S.ctx[tid]       = uvv / fmaxf((float)t1, 1.0f);
  S.ctx[256 + tid] = current[b * D_SZ + tid];
  S.ctx[512 + tid] = depot[b * D_SZ + tid];
  __syncthreads();
  if (tid == 0) {  // vm[0] = !all(vm[1:])
    int all1 = 1;
    for (int c = 1; c < NCL; ++c) all1 &= S.vm[c];
    S.vm[0] = all1 ? 0 : 1;
  }

  // --- q[j] = ctx . Wq[:,j], j = tid ---
  {
    float a0 = 0.f, a1 = 0.f, a2 = 0.f, a3 = 0.f;
    for (int i = 0; i < 3 * D_SZ; i += 4) {
      a0 = fmaf(S.ctx[i + 0], Wq[(size_t)(i + 0) * D_SZ + tid], a0);
      a1 = fmaf(S.ctx[i + 1], Wq[(size_t)(i + 1) * D_SZ + tid], a1);
      a2 = fmaf(S.ctx[i + 2], Wq[(size_t)(i + 2) * D_SZ + tid], a2);
      a3 = fmaf(S.ctx[i + 3], Wq[(size_t)(i + 3) * D_SZ + tid], a3);
    }
    S.q[tid] = (a0 + a1) + (a2 + a3);
  }
  __syncthreads();

  // --- tT[h][i] = sum_e Wk[i, h*16+e] * q[h*16+e] ---
  {
    const int h = tid & 15, i0 = tid >> 4;
    float qh[16];
    #pragma unroll
    for (int e = 0; e < 16; ++e) qh[e] = S.q[h * 16 + e];
    for (int k = 0; k < 16; ++k) {
      const int i = i0 + 16 * k;
      const float* wr = Wk + (size_t)i * D_SZ + h * 16;
      float acc = 0.f;
      #pragma unroll
      for (int e = 0; e < 16; ++e) acc = fmaf(wr[e], qh[e], acc);
      S.tu.tT[h][i] = acc;
    }
  }
  __syncthreads();

  // --- scores[h][c] = 0.25 * sum_i A[c,i] * tT[h][i], chunked over c ---
  for (int ch = 0; ch < 7; ++ch) {
    const int r0 = ch * 16;
    for (int x = tid; x < 16 * 64; x += 256) {
      const int r = x >> 6, cc = (x & 63) << 2;
      if (r0 + r < NCL) {
        const float4 v = *(const float4*)(Ab + (size_t)(r0 + r) * D_SZ + cc);
        *(float4*)&S.At[r][cc] = v;
      }
    }
    __syncthreads();
    {
      const int h = tid >> 4, cl = tid & 15, c = r0 + cl;
      float p0 = 0.f, p1 = 0.f, p2 = 0.f, p3 = 0.f;
      for (int i = 0; i < D_SZ; i += 4) {
        const float4 av = *(const float4*)&S.At[cl][i];
        const float4 tv = *(const float4*)&S.tu.tT[h][i];
        p0 = fmaf(av.x, tv.x, p0);
        p1 = fmaf(av.y, tv.y, p1);
        p2 = fmaf(av.z, tv.z, p2);
        p3 = fmaf(av.w, tv.w, p3);
      }
      if (c < NCL) {
        float sv = 0.25f * ((p0 + p1) + (p2 + p3));
        if (S.vm[c]) sv = NEGV;
        S.sc[h][c] = sv;
      }
    }
    __syncthreads();
  }

  // --- softmax per head (16 lanes per head) ---
  {
    const int h = tid >> 4, j = tid & 15;
    float m = -3.0e38f;
    for (int c = j; c < NCL; c += 16) m = fmaxf(m, S.sc[h][c]);
    #pragma unroll
    for (int off = 8; off > 0; off >>= 1) m = fmaxf(m, __shfl_xor(m, off, 16));
    float ssum = 0.f;
    for (int c = j; c < NCL; c += 16) {
      const float e = expf(S.sc[h][c] - m);
      S.sc[h][c] = e;
      ssum += e;
    }
    #pragma unroll
    for (int off = 8; off > 0; off >>= 1) ssum += __shfl_xor(ssum, off, 16);
    const float inv = 1.0f / ssum;
    for (int c = j; c < NCL; c += 16) S.sc[h][c] *= inv;
  }
  __syncthreads();

  // --- u[h][i] = sum_c attn[h,c] * A[c,i]; thread owns column i = tid ---
  {
    float u[16];
    #pragma unroll
    for (int h = 0; h < 16; ++h) u[h] = 0.f;
    for (int ch = 0; ch < 7; ++ch) {
      const int r0 = ch * 16;
      for (int x = tid; x < 16 * 64; x += 256) {
        const int r = x >> 6, cc = (x & 63) << 2;
        if (r0 + r < NCL) {
          const float4 v = *(const float4*)(Ab + (size_t)(r0 + r) * D_SZ + cc);
          *(float4*)&S.At[r][cc] = v;
        }
      }
      __syncthreads();
      const int cmax = (NCL - r0 < 16) ? (NCL - r0) : 16;
      for (int cl = 0; cl < cmax; ++cl) {
        const float a = S.At[cl][tid];
        const int c = r0 + cl;
        #pragma unroll
        for (int h = 0; h < 16; ++h) u[h] = fmaf(S.sc[h][c], a, u[h]);
      }
      __syncthreads();
    }
    #pragma unroll
    for (int h = 0; h < 16; ++h) S.tu.uB[h][tid] = u[h];  // tT dead now
  }
  __syncthreads();

  // --- glimpse: g[h*16+e] = sum_i u[h][i] * Wv[i, h*16+e]; (h*16+e) == tid ---
  {
    const int h = tid >> 4;
    float p0 = 0.f, p1 = 0.f, p2 = 0.f, p3 = 0.f;
    for (int i = 0; i < D_SZ; i += 4) {
      p0 = fmaf(S.tu.uB[h][i + 0], Wv[(size_t)(i + 0) * D_SZ + tid], p0);
      p1 = fmaf(S.tu.uB[h][i + 1], Wv[(size_t)(i + 1) * D_SZ + tid], p1);
      p2 = fmaf(S.tu.uB[h][i + 2], Wv[(size_t)(i + 2) * D_SZ + tid], p2);
      p3 = fmaf(S.tu.uB[h][i + 3], Wv[(size_t)(i + 3) * D_SZ + tid], p3);
    }
    S.g[tid] = (p0 + p1) + (p2 + p3);
  }
  __syncthreads();

  // --- go[j] = sum_d g[d] * Wo[d,j] ---
  {
    float p0 = 0.f, p1 = 0.f, p2 = 0.f, p3 = 0.f;
    for (int d = 0; d < D_SZ; d += 4) {
      p0 = fmaf(S.g[d + 0], Wo[(size_t)(d + 0) * D_SZ + tid], p0);
      p1 = fmaf(S.g[d + 1], Wo[(size_t)(d + 1) * D_SZ + tid], p1);
      p2 = fmaf(S.g[d + 2], Wo[(size_t)(d + 2) * D_SZ + tid], p2);
      p3 = fmaf(S.g[d + 3], Wo[(size_t)(d + 3) * D_SZ + tid], p3);
    }
    S.go[tid] = (p0 + p1) + (p2 + p3);
  }
  __syncthreads();

  // --- w[i] = sum_j Wks[i,j] * go[j]; thread streams row i = tid ---
  {
    const float* wr = Wks + (size_t)tid * D_SZ;
    float p0 = 0.f, p1 = 0.f, p2 = 0.f, p3 = 0.f;
    for (int j = 0; j < D_SZ; j += 4) {
      const float4 w4 = *(const float4*)&wr[j];
      p0 = fmaf(w4.x, S.go[j + 0], p0);
      p1 = fmaf(w4.y, S.go[j + 1], p1);
      p2 = fmaf(w4.z, S.go[j + 2], p2);
      p3 = fmaf(w4.w, S.go[j + 3], p3);
    }
    S.w[tid] = (p0 + p1) + (p2 + p3);
  }
  __syncthreads();

  // --- logits[c] = tanh((A[c,:].w)/16)*10, masked ---
  if (tid < NCL) {
    const float* ar = Ab + (size_t)tid * D_SZ;
    float p0 = 0.f, p1 = 0.f, p2 = 0.f, p3 = 0.f;
    for (int i = 0; i < D_SZ; i += 4) {
      const float4 a4 = *(const float4*)&ar[i];
      p0 = fmaf(a4.x, S.w[i + 0], p0);
      p1 = fmaf(a4.y, S.w[i + 1], p1);
      p2 = fmaf(a4.z, S.w[i + 2], p2);
      p3 = fmaf(a4.w, S.w[i + 3], p3);
    }
    float l = ((p0 + p1) + (p2 + p3)) * 0.0625f;
    l = tanhf(l) * 10.0f;
    if (S.vm[tid]) l = NEGV;
    S.logits[tid] = l;
  }
  __syncthreads();

  // --- logsumexp + argmax (wave 0) ---
  if (tid < 64) {
    float bv = -3.0e38f; int bi = 0;
    for (int c = tid; c < NCL; c += 64) {
      const float v = S.logits[c];
      if (v > bv) { bv = v; bi = c; }
    }
    #pragma unroll
    for (int off = 32; off > 0; off >>= 1) {
      const float ov = __shfl_xor(bv, off);
      const int   oi = __shfl_xor(bi, off);
      if (ov > bv || (ov == bv && oi < bi)) { bv = ov; bi = oi; }
    }
    float ss = 0.f;
    for (int c = tid; c < NCL; c += 64) ss += expf(S.logits[c] - bv);
    #pragma unroll
    for (int off = 32; off > 0; off >>= 1) ss += __shfl_xor(ss, off);
    if (tid == 0) { S.lse_s = bv + logf(ss); S.sel_s = bi; }
  }
  __syncthreads();

  // --- outputs ---
  // layout: init_aug [B,1024] @0; guid_emb [B,256] @262144; guid [B] @327680; clu_prob [B,101] @327936
  const float lse = S.lse_s;
  const int sel = S.sel_s;
  if (tid < NCL) out[327936 + b * NCL + tid] = S.logits[tid] - lse;
  if (tid == 0)  out[327680 + b] = (float)sel;
  const float se = Ab[(size_t)sel * D_SZ + tid];
  out[262144 + b * D_SZ + tid] = se;
  float* ia = out + (size_t)b * 1024;
  ia[tid]       = uvcval;
  ia[256 + tid] = current[b * D_SZ + tid];
  ia[512 + tid] = se;
  ia[768 + tid] = depot[b * D_SZ + tid];
}

extern "C" void kernel_launch(void* const* d_in, const int* in_sizes, int n_in,
                              void* d_out, int out_size, void* d_ws, size_t ws_size,
                              hipStream_t stream) {
  const float* depot   = (const float*)d_in[0];
  const float* cluster = (const float*)d_in[1];
  const float* current = (const float*)d_in[2];
  const float* node    = (const float*)d_in[3];
  const void*  mask    = d_in[4];
  const void*  cmask   = d_in[5];
  const void*  vcm     = d_in[6];
  const float* Wq  = (const float*)d_in[7];
  const float* Wk  = (const float*)d_in[8];
  const float* Wv  = (const float*)d_in[9];
  const float* Wks = (const float*)d_in[10];
  const float* Wo  = (const float*)d_in[11];
  float* out = (float*)d_out;

  int*   flag     = (int*)d_ws;
  int*   counts   = (int*)((char*)d_ws + 1024);
  float* partials = (float*)((char*)d_ws + 1024 + 16384);

  hipLaunchKernelGGL(detect_mode_kernel, dim3(1), dim3(64), 0, stream,
                     (const unsigned int*)mask, flag);
  hipLaunchKernelGGL(mean_partial_kernel, dim3(B_SZ * 8), dim3(256), 0, stream,
                     node, mask, cmask, flag, counts, partials);
  hipLaunchKernelGGL(main_kernel, dim3(B_SZ), dim3(256), 0, stream,
                     depot, cluster, current, vcm, flag,
                     Wq, Wk, Wv, Wks, Wo, counts, partials, out);
}